// Round 8
// baseline (169.339 us; speedup 1.0000x reference)
//
#include <hip/hip_runtime.h>

typedef _Float16 f16;
typedef __fp16 fp16x2 __attribute__((ext_vector_type(2)));
typedef _Float16 half4 __attribute__((ext_vector_type(4)));
typedef _Float16 half8 __attribute__((ext_vector_type(8)));
typedef float f32x4 __attribute__((ext_vector_type(4)));
typedef float float4v __attribute__((ext_vector_type(4)));

#define LOG2E 1.44269504088896340736f

__device__ __forceinline__ half8 cat8(half4 a, half4 b) {
    half8 r;
    r[0] = a[0]; r[1] = a[1]; r[2] = a[2]; r[3] = a[3];
    r[4] = b[0]; r[5] = b[1]; r[6] = b[2]; r[7] = b[3];
    return r;
}

union H8 { fp16x2 h2[4]; half8 h8; };

// 8 transpose-reads: pairs (db*128, db*128+512) = A-frag halves for db=0..3.
// "=&v" early-clobber: outputs must never alias the address input.
#define TR8(baddr, d0,d1,d2,d3,d4,d5,d6,d7)                                   \
  asm volatile("ds_read_b64_tr_b16 %0, %8 offset:0\n\t"                       \
               "ds_read_b64_tr_b16 %1, %8 offset:512\n\t"                     \
               "ds_read_b64_tr_b16 %2, %8 offset:128\n\t"                     \
               "ds_read_b64_tr_b16 %3, %8 offset:640\n\t"                     \
               "ds_read_b64_tr_b16 %4, %8 offset:256\n\t"                     \
               "ds_read_b64_tr_b16 %5, %8 offset:768\n\t"                     \
               "ds_read_b64_tr_b16 %6, %8 offset:384\n\t"                     \
               "ds_read_b64_tr_b16 %7, %8 offset:896"                         \
               : "=&v"(d0),"=&v"(d1),"=&v"(d2),"=&v"(d3),                     \
                 "=&v"(d4),"=&v"(d5),"=&v"(d6),"=&v"(d7)                      \
               : "v"(baddr) : "memory")

#define LGKM0_FENCE()                                                          \
  do { asm volatile("s_waitcnt lgkmcnt(0)" ::: "memory");                      \
       __builtin_amdgcn_sched_barrier(0); } while (0)

// in-register online softmax + P packing (round-7-proven semantics)
__device__ __forceinline__ void softmax_pack(
    f32x4 sf[4], float& mL, float& l, f32x4 o[4], H8& pb0, H8& pb1)
{
    float vm01 = fmaxf(fmaxf(fmaxf(sf[0][0], sf[0][1]), fmaxf(sf[0][2], sf[0][3])),
                       fmaxf(fmaxf(sf[1][0], sf[1][1]), fmaxf(sf[1][2], sf[1][3])));
    float vm23 = fmaxf(fmaxf(fmaxf(sf[2][0], sf[2][1]), fmaxf(sf[2][2], sf[2][3])),
                       fmaxf(fmaxf(sf[3][0], sf[3][1]), fmaxf(sf[3][2], sf[3][3])));
    float vm = fmaxf(vm01, vm23);
    vm = fmaxf(vm, __shfl_xor(vm, 16, 64));
    vm = fmaxf(vm, __shfl_xor(vm, 32, 64));
    float vmL = vm * LOG2E;

    // defer-max: rescale only when the row max grows by >8 (log2 units)
    if (__any(vmL > mL + 8.0f)) {
        float mn = fmaxf(mL, vmL);
        float al = __builtin_amdgcn_exp2f(mL - mn);
        l *= al;
        #pragma unroll
        for (int db = 0; db < 4; ++db) o[db] *= al;
        mL = mn;
    }

    f32x4 pe[4];
    float rs = 0.0f;
    #pragma unroll
    for (int kb = 0; kb < 4; ++kb) {
        #pragma unroll
        for (int ro = 0; ro < 4; ++ro) {
            float p = __builtin_amdgcn_exp2f(fmaf(sf[kb][ro], LOG2E, -mL));
            pe[kb][ro] = p;
            rs += p;
        }
    }
    rs += __shfl_xor(rs, 16, 64);
    rs += __shfl_xor(rs, 32, 64);
    l += rs;

    pb0.h2[0] = __builtin_amdgcn_cvt_pkrtz(pe[0][0], pe[0][1]);
    pb0.h2[1] = __builtin_amdgcn_cvt_pkrtz(pe[0][2], pe[0][3]);
    pb0.h2[2] = __builtin_amdgcn_cvt_pkrtz(pe[1][0], pe[1][1]);
    pb0.h2[3] = __builtin_amdgcn_cvt_pkrtz(pe[1][2], pe[1][3]);
    pb1.h2[0] = __builtin_amdgcn_cvt_pkrtz(pe[2][0], pe[2][1]);
    pb1.h2[1] = __builtin_amdgcn_cvt_pkrtz(pe[2][2], pe[2][3]);
    pb1.h2[2] = __builtin_amdgcn_cvt_pkrtz(pe[3][0], pe[3][1]);
    pb1.h2[3] = __builtin_amdgcn_cvt_pkrtz(pe[3][2], pe[3][3]);
}

// ---------------------------------------------------------------------------
// QKV projection (unchanged)
// ---------------------------------------------------------------------------
__global__ __launch_bounds__(256) void qkv_proj(
    const float* __restrict__ Aq, const float* __restrict__ Ak, const float* __restrict__ Av,
    const float* __restrict__ Wq, const float* __restrict__ Wk, const float* __restrict__ Wv,
    const float* __restrict__ bq, const float* __restrict__ bk, const float* __restrict__ bv,
    f16* __restrict__ Qh, f16* __restrict__ Kh, f16* __restrict__ Vh)
{
    const int z = blockIdx.z;
    const float* __restrict__ A    = (z == 0) ? Aq : (z == 1) ? Ak : Av;
    const float* __restrict__ W    = (z == 0) ? Wq : (z == 1) ? Wk : Wv;
    const float* __restrict__ bias = (z == 0) ? bq : (z == 1) ? bk : bv;
    f16* __restrict__ dst          = (z == 0) ? Qh : (z == 1) ? Kh : Vh;

    __shared__ __align__(16) f16 As[128 * 40];
    __shared__ __align__(16) f16 Ws[128 * 40];

    const int t  = threadIdx.x;
    const int m0 = blockIdx.y * 128;
    const int n0 = blockIdx.x * 128;
    const int w = t >> 6, lane = t & 63, lr = lane & 15, lg = lane >> 4;
    const int wr = w >> 1, wc = w & 1;

    f32x4 acc[4][4] = {};

    for (int k0 = 0; k0 < 512; k0 += 32) {
        #pragma unroll
        for (int it = 0; it < 2; ++it) {
            int c = t + it * 256;
            int row  = c >> 2;
            int col8 = (c & 3) * 8;

            const float* ga = A + (size_t)(m0 + row) * 512 + k0 + col8;
            float4v a0 = *(const float4v*)ga;
            float4v a1 = *(const float4v*)(ga + 4);
            half8 ha;
            ha[0] = (f16)a0[0]; ha[1] = (f16)a0[1]; ha[2] = (f16)a0[2]; ha[3] = (f16)a0[3];
            ha[4] = (f16)a1[0]; ha[5] = (f16)a1[1]; ha[6] = (f16)a1[2]; ha[7] = (f16)a1[3];
            *(half8*)&As[row * 40 + col8] = ha;

            const float* gw = W + (size_t)(n0 + row) * 512 + k0 + col8;
            float4v w0 = *(const float4v*)gw;
            float4v w1 = *(const float4v*)(gw + 4);
            half8 hw;
            hw[0] = (f16)w0[0]; hw[1] = (f16)w0[1]; hw[2] = (f16)w0[2]; hw[3] = (f16)w0[3];
            hw[4] = (f16)w1[0]; hw[5] = (f16)w1[1]; hw[6] = (f16)w1[2]; hw[7] = (f16)w1[3];
            *(half8*)&Ws[row * 40 + col8] = hw;
        }
        __syncthreads();

        half8 af[4], bf[4];
        #pragma unroll
        for (int i = 0; i < 4; ++i) {
            af[i] = *(const half8*)&As[(wr * 64 + i * 16 + lr) * 40 + lg * 8];
            bf[i] = *(const half8*)&Ws[(wc * 64 + i * 16 + lr) * 40 + lg * 8];
        }
        #pragma unroll
        for (int mi = 0; mi < 4; ++mi)
            #pragma unroll
            for (int ni = 0; ni < 4; ++ni)
                acc[mi][ni] = __builtin_amdgcn_mfma_f32_16x16x32_f16(af[mi], bf[ni], acc[mi][ni], 0, 0, 0);
        __syncthreads();
    }

    #pragma unroll
    for (int mi = 0; mi < 4; ++mi) {
        #pragma unroll
        for (int ni = 0; ni < 4; ++ni) {
            int col = n0 + wc * 64 + ni * 16 + lr;
            float bv_ = bias[col];
            int h  = col >> 6;
            int dd = col & 63;
            #pragma unroll
            for (int r = 0; r < 4; ++r) {
                int row = m0 + wr * 64 + mi * 16 + lg * 4 + r;
                int b = row >> 12;
                int s = row & 4095;
                dst[(((size_t)(b * 8 + h)) * 4096 + s) * 64 + dd] = (f16)(acc[mi][ni][r] + bv_);
            }
        }
    }
}

// ---------------------------------------------------------------------------
// Flash attention v7 = round-7 kernel reshaped to 4 waves / 256 threads,
// grid 512 blocks (2 blocks/CU, 16 waves/CU) for cross-block latency hiding.
// Each wave owns TWO 16-row q-groups sharing kf and ua/ub fragments.
// Staging: each thread stages key-rows srow and srow+32 (verified offsets).
// All compute/fence/barrier structure identical to round 7 (passing).
// ---------------------------------------------------------------------------
__global__ __launch_bounds__(256, 2) void flash_attn(
    const f16* __restrict__ Qh, const f16* __restrict__ Kh, const f16* __restrict__ Vh,
    f16* __restrict__ Xh)
{
    const int bh  = blockIdx.y;           // 0..15  (b*8 + h)
    const int t = threadIdx.x, w = t >> 6, lane = t & 63, lr = lane & 15, lg = lane >> 4;
    const int q0 = blockIdx.x * 128 + w * 32;

    __shared__ __align__(16) f16 Ks[2][64 * 72];   // [key][d], stride 72
    __shared__ __align__(16) f16 Vs[2][64 * 64];   // subtiled for tr_b16 reads

    const size_t hb = (size_t)bh * (4096 * 64);

    // Q fragments (B-operand of swapped QK^T) for both 16-row groups
    half8 aq00 = *(const half8*)&Qh[hb + (size_t)(q0 + lr) * 64 + lg * 8];
    half8 aq01 = *(const half8*)&Qh[hb + (size_t)(q0 + lr) * 64 + 32 + lg * 8];
    half8 aq10 = *(const half8*)&Qh[hb + (size_t)(q0 + 16 + lr) * 64 + lg * 8];
    half8 aq11 = *(const half8*)&Qh[hb + (size_t)(q0 + 16 + lr) * 64 + 32 + lg * 8];

    // staging: 256 threads x 2 key-rows x 8 f16 per buffer
    const int srow = t >> 3;            // key index 0..31 (plus srow+32)
    const int scol = (t & 7) * 8;       // d index
    const int kdstA = srow * 72 + scol;
    const int kdstB = kdstA + 32 * 72;
    const int vdstA = ((((srow >> 2) & 3) * 16) + (srow >> 4) * 4 + (scol >> 4)) * 64
                    + (srow & 3) * 16 + (scol & 15);
    const int vdstB = vdstA + 512;      // vdst(srow+32) == vdst(srow) + 512

    f32x4 o0[4] = {}, o1[4] = {};
    float mL0 = -INFINITY, l0 = 0.0f, mL1 = -INFINITY, l1 = 0.0f;

    const f16* kbase = Kh + hb + (size_t)srow * 64 + scol;
    const f16* vbase = Vh + hb + (size_t)srow * 64 + scol;

    half8 kregA = *(const half8*)kbase;
    half8 kregB = *(const half8*)(kbase + 2048);
    half8 vregA = *(const half8*)vbase;
    half8 vregB = *(const half8*)(vbase + 2048);

    for (int kt = 0; kt < 4096; kt += 64) {
        const int bi = (kt >> 6) & 1;
        f16* ks = &Ks[bi][0];
        f16* vs = &Vs[bi][0];

        *(half8*)&ks[kdstA] = kregA;
        *(half8*)&ks[kdstB] = kregB;
        *(half8*)&vs[vdstA] = vregA;
        *(half8*)&vs[vdstB] = vregB;
        __syncthreads();

        // prefetch next tile into regs (hides HBM under compute)
        int koff = ((kt + 64) & 4095) << 6;
        kregA = *(const half8*)(kbase + koff);
        kregB = *(const half8*)(kbase + 2048 + koff);
        vregA = *(const half8*)(vbase + koff);
        vregB = *(const half8*)(vbase + 2048 + koff);

        // ---- S^T = K Q^T for both q-groups; kf loaded once, used twice ----
        f32x4 sf0[4] = {}, sf1[4] = {};
        #pragma unroll
        for (int c = 0; c < 2; ++c) {
            half8 kf[4];
            #pragma unroll
            for (int kb = 0; kb < 4; ++kb)
                kf[kb] = *(const half8*)&ks[(kb * 16 + lr) * 72 + c * 32 + lg * 8];
            half8 a0 = c ? aq01 : aq00;
            half8 a1 = c ? aq11 : aq10;
            __builtin_amdgcn_s_setprio(1);
            #pragma unroll
            for (int kb = 0; kb < 4; ++kb)
                sf0[kb] = __builtin_amdgcn_mfma_f32_16x16x32_f16(kf[kb], a0, sf0[kb], 0, 0, 0);
            #pragma unroll
            for (int kb = 0; kb < 4; ++kb)
                sf1[kb] = __builtin_amdgcn_mfma_f32_16x16x32_f16(kf[kb], a1, sf1[kb], 0, 0, 0);
            __builtin_amdgcn_s_setprio(0);
        }

        // ---- softmax + P packing, both groups (in-register) ----
        H8 p00, p01, p10, p11;
        softmax_pack(sf0, mL0, l0, o0, p00, p01);
        softmax_pack(sf1, mL1, l1, o1, p10, p11);

        // ---- O^T += V^T P^T : TR8 -> fence -> MFMAs, V shared by groups ----
        const unsigned vb = (unsigned)(size_t)vs + (unsigned)(lg * 2048 + lr * 8);
        {
            half4 u0,u1,u2,u3,u4,u5,u6,u7;
            TR8(vb, u0,u1,u2,u3,u4,u5,u6,u7);
            LGKM0_FENCE();
            __builtin_amdgcn_s_setprio(1);
            o0[0] = __builtin_amdgcn_mfma_f32_16x16x32_f16(cat8(u0,u1), p00.h8, o0[0], 0, 0, 0);
            o0[1] = __builtin_amdgcn_mfma_f32_16x16x32_f16(cat8(u2,u3), p00.h8, o0[1], 0, 0, 0);
            o0[2] = __builtin_amdgcn_mfma_f32_16x16x32_f16(cat8(u4,u5), p00.h8, o0[2], 0, 0, 0);
            o0[3] = __builtin_amdgcn_mfma_f32_16x16x32_f16(cat8(u6,u7), p00.h8, o0[3], 0, 0, 0);
            o1[0] = __builtin_amdgcn_mfma_f32_16x16x32_f16(cat8(u0,u1), p10.h8, o1[0], 0, 0, 0);
            o1[1] = __builtin_amdgcn_mfma_f32_16x16x32_f16(cat8(u2,u3), p10.h8, o1[1], 0, 0, 0);
            o1[2] = __builtin_amdgcn_mfma_f32_16x16x32_f16(cat8(u4,u5), p10.h8, o1[2], 0, 0, 0);
            o1[3] = __builtin_amdgcn_mfma_f32_16x16x32_f16(cat8(u6,u7), p10.h8, o1[3], 0, 0, 0);
            __builtin_amdgcn_s_setprio(0);
            TR8(vb + 1024u, u0,u1,u2,u3,u4,u5,u6,u7);
            LGKM0_FENCE();
            __builtin_amdgcn_s_setprio(1);
            o0[0] = __builtin_amdgcn_mfma_f32_16x16x32_f16(cat8(u0,u1), p01.h8, o0[0], 0, 0, 0);
            o0[1] = __builtin_amdgcn_mfma_f32_16x16x32_f16(cat8(u2,u3), p01.h8, o0[1], 0, 0, 0);
            o0[2] = __builtin_amdgcn_mfma_f32_16x16x32_f16(cat8(u4,u5), p01.h8, o0[2], 0, 0, 0);
            o0[3] = __builtin_amdgcn_mfma_f32_16x16x32_f16(cat8(u6,u7), p01.h8, o0[3], 0, 0, 0);
            o1[0] = __builtin_amdgcn_mfma_f32_16x16x32_f16(cat8(u0,u1), p11.h8, o1[0], 0, 0, 0);
            o1[1] = __builtin_amdgcn_mfma_f32_16x16x32_f16(cat8(u2,u3), p11.h8, o1[1], 0, 0, 0);
            o1[2] = __builtin_amdgcn_mfma_f32_16x16x32_f16(cat8(u4,u5), p11.h8, o1[2], 0, 0, 0);
            o1[3] = __builtin_amdgcn_mfma_f32_16x16x32_f16(cat8(u6,u7), p11.h8, o1[3], 0, 0, 0);
            __builtin_amdgcn_s_setprio(0);
        }
    }

    // ---- epilogue: O/(l*8) per group, write (b, s, h, dd) fp16 ----
    const int b = bh >> 3, h = bh & 7;
    const float inv0 = 1.0f / (l0 * 8.0f);
    const float inv1 = 1.0f / (l1 * 8.0f);
    const int q0_ = q0 + lr, q1_ = q0 + 16 + lr;
    #pragma unroll
    for (int db = 0; db < 4; ++db) {
        half4 hv0, hv1;
        hv0[0] = (f16)(o0[db][0] * inv0);
        hv0[1] = (f16)(o0[db][1] * inv0);
        hv0[2] = (f16)(o0[db][2] * inv0);
        hv0[3] = (f16)(o0[db][3] * inv0);
        *(half4*)&Xh[((size_t)(b * 4096 + q0_)) * 512 + h * 64 + db * 16 + lg * 4] = hv0;
        hv1[0] = (f16)(o1[db][0] * inv1);
        hv1[1] = (f16)(o1[db][1] * inv1);
        hv1[2] = (f16)(o1[db][2] * inv1);
        hv1[3] = (f16)(o1[db][3] * inv1);
        *(half4*)&Xh[((size_t)(b * 4096 + q1_)) * 512 + h * 64 + db * 16 + lg * 4] = hv1;
    }
}

// ---------------------------------------------------------------------------
// Output projection (unchanged)
// ---------------------------------------------------------------------------
__global__ __launch_bounds__(256) void out_proj(
    const f16* __restrict__ Xh, const float* __restrict__ Wo, const float* __restrict__ bo,
    float* __restrict__ out)
{
    __shared__ __align__(16) f16 As[128 * 40];
    __shared__ __align__(16) f16 Ws[128 * 40];

    const int t  = threadIdx.x;
    const int m0 = blockIdx.y * 128;
    const int n0 = blockIdx.x * 128;
    const int w = t >> 6, lane = t & 63, lr = lane & 15, lg = lane >> 4;
    const int wr = w >> 1, wc = w & 1;

    f32x4 acc[4][4] = {};

    for (int k0 = 0; k0 < 512; k0 += 32) {
        #pragma unroll
        for (int it = 0; it < 2; ++it) {
            int c = t + it * 256;
            int row  = c >> 2;
            int col8 = (c & 3) * 8;

            *(half8*)&As[row * 40 + col8] =
                *(const half8*)&Xh[(size_t)(m0 + row) * 512 + k0 + col8];

            const float* gw = Wo + (size_t)(n0 + row) * 512 + k0 + col8;
            float4v w0 = *(const float4v*)gw;
            float4v w1 = *(const float4v*)(gw + 4);
            half8 hw;
            hw[0] = (f16)w0[0]; hw[1] = (f16)w0[1]; hw[2] = (f16)w0[2]; hw[3] = (f16)w0[3];
            hw[4] = (f16)w1[0]; hw[5] = (f16)w1[1]; hw[6] = (f16)w1[2]; hw[7] = (f16)w1[3];
            *(half8*)&Ws[row * 40 + col8] = hw;
        }
        __syncthreads();

        half8 af[4], bf[4];
        #pragma unroll
        for (int i = 0; i < 4; ++i) {
            af[i] = *(const half8*)&As[(wr * 64 + i * 16 + lr) * 40 + lg * 8];
            bf[i] = *(const half8*)&Ws[(wc * 64 + i * 16 + lr) * 40 + lg * 8];
        }
        #pragma unroll
        for (int mi = 0; mi < 4; ++mi)
            #pragma unroll
            for (int ni = 0; ni < 4; ++ni)
                acc[mi][ni] = __builtin_amdgcn_mfma_f32_16x16x32_f16(af[mi], bf[ni], acc[mi][ni], 0, 0, 0);
        __syncthreads();
    }

    #pragma unroll
    for (int mi = 0; mi < 4; ++mi) {
        #pragma unroll
        for (int ni = 0; ni < 4; ++ni) {
            int col = n0 + wc * 64 + ni * 16 + lr;
            float bb = bo[col];
            #pragma unroll
            for (int r = 0; r < 4; ++r) {
                int row = m0 + wr * 64 + mi * 16 + lg * 4 + r;
                out[(size_t)row * 512 + col] = acc[mi][ni][r] + bb;
            }
        }
    }
}

// ---------------------------------------------------------------------------
extern "C" void kernel_launch(void* const* d_in, const int* in_sizes, int n_in,
                              void* d_out, int out_size, void* d_ws, size_t ws_size,
                              hipStream_t stream) {
    const float* query = (const float*)d_in[0];
    const float* key   = (const float*)d_in[1];
    const float* value = (const float*)d_in[2];
    const float* Wq    = (const float*)d_in[3];
    const float* bq    = (const float*)d_in[4];
    const float* Wk    = (const float*)d_in[5];
    const float* bk    = (const float*)d_in[6];
    const float* Wv    = (const float*)d_in[7];
    const float* bv    = (const float*)d_in[8];
    const float* Wo    = (const float*)d_in[9];
    const float* bo    = (const float*)d_in[10];
    float* out = (float*)d_out;

    char* ws = (char*)d_ws;
    f16* Qh = (f16*)(ws);
    f16* Kh = (f16*)(ws + 8388608);
    f16* Vh = (f16*)(ws + 16777216);
    f16* Xh = (f16*)(ws + 25165824);

    qkv_proj<<<dim3(4, 64, 3), 256, 0, stream>>>(query, key, value,
                                                 Wq, Wk, Wv, bq, bk, bv,
                                                 Qh, Kh, Vh);
    flash_attn<<<dim3(32, 16), 256, 0, stream>>>(Qh, Kh, Vh, Xh);
    out_proj<<<dim3(4, 64), 256, 0, stream>>>(Xh, Wo, bo, out);
}

// Round 9
// 164.565 us; speedup vs baseline: 1.0290x; 1.0290x over previous
//
#include <hip/hip_runtime.h>

typedef _Float16 f16;
typedef __fp16 fp16x2 __attribute__((ext_vector_type(2)));
typedef _Float16 half4 __attribute__((ext_vector_type(4)));
typedef _Float16 half8 __attribute__((ext_vector_type(8)));
typedef float f32x4 __attribute__((ext_vector_type(4)));
typedef float float4v __attribute__((ext_vector_type(4)));

#define LOG2E 1.44269504088896340736f

__device__ __forceinline__ half8 cat8(half4 a, half4 b) {
    half8 r;
    r[0] = a[0]; r[1] = a[1]; r[2] = a[2]; r[3] = a[3];
    r[4] = b[0]; r[5] = b[1]; r[6] = b[2]; r[7] = b[3];
    return r;
}

union H8 { fp16x2 h2[4]; half8 h8; };

// 8 transpose-reads: pairs (db*128, db*128+512) = A-frag halves for db=0..3.
// "=&v" early-clobber: outputs must never alias the address input.
#define TR8(baddr, d0,d1,d2,d3,d4,d5,d6,d7)                                   \
  asm volatile("ds_read_b64_tr_b16 %0, %8 offset:0\n\t"                       \
               "ds_read_b64_tr_b16 %1, %8 offset:512\n\t"                     \
               "ds_read_b64_tr_b16 %2, %8 offset:128\n\t"                     \
               "ds_read_b64_tr_b16 %3, %8 offset:640\n\t"                     \
               "ds_read_b64_tr_b16 %4, %8 offset:256\n\t"                     \
               "ds_read_b64_tr_b16 %5, %8 offset:768\n\t"                     \
               "ds_read_b64_tr_b16 %6, %8 offset:384\n\t"                     \
               "ds_read_b64_tr_b16 %7, %8 offset:896"                         \
               : "=&v"(d0),"=&v"(d1),"=&v"(d2),"=&v"(d3),                     \
                 "=&v"(d4),"=&v"(d5),"=&v"(d6),"=&v"(d7)                      \
               : "v"(baddr) : "memory")

#define LGKM0_FENCE()                                                          \
  do { asm volatile("s_waitcnt lgkmcnt(0)" ::: "memory");                      \
       __builtin_amdgcn_sched_barrier(0); } while (0)

__device__ __forceinline__ float rowmax16(const f32x4 sf[4]) {
    float a = fmaxf(fmaxf(sf[0][0], sf[0][1]), fmaxf(sf[0][2], sf[0][3]));
    float b = fmaxf(fmaxf(sf[1][0], sf[1][1]), fmaxf(sf[1][2], sf[1][3]));
    float c = fmaxf(fmaxf(sf[2][0], sf[2][1]), fmaxf(sf[2][2], sf[2][3]));
    float d = fmaxf(fmaxf(sf[3][0], sf[3][1]), fmaxf(sf[3][2], sf[3][3]));
    return fmaxf(fmaxf(a, b), fmaxf(c, d));
}

// running-max update with defer threshold; rescales o and the MFMA-held l.
__device__ __forceinline__ void max_defer(
    const f32x4 sf[4], float& mL, f32x4 o[4], f32x4& la)
{
    float vm = rowmax16(sf);
    vm = fmaxf(vm, __shfl_xor(vm, 16, 64));
    vm = fmaxf(vm, __shfl_xor(vm, 32, 64));
    float vmL = vm * LOG2E;
    if (__any(vmL > mL + 8.0f)) {
        float mn = fmaxf(mL, vmL);
        float al = __builtin_amdgcn_exp2f(mL - mn);
        la *= al;
        #pragma unroll
        for (int db = 0; db < 4; ++db) o[db] *= al;
        mL = mn;
    }
}

// P = exp2(S*log2e - mL), packed to fp16 B-fragments (pure VALU, no lgkm).
__device__ __forceinline__ void exp_pack(
    const f32x4 sf[4], float mL, H8& pb0, H8& pb1)
{
    float pe[16];
    #pragma unroll
    for (int kb = 0; kb < 4; ++kb)
        #pragma unroll
        for (int ro = 0; ro < 4; ++ro)
            pe[kb * 4 + ro] = __builtin_amdgcn_exp2f(fmaf(sf[kb][ro], LOG2E, -mL));
    pb0.h2[0] = __builtin_amdgcn_cvt_pkrtz(pe[0],  pe[1]);
    pb0.h2[1] = __builtin_amdgcn_cvt_pkrtz(pe[2],  pe[3]);
    pb0.h2[2] = __builtin_amdgcn_cvt_pkrtz(pe[4],  pe[5]);
    pb0.h2[3] = __builtin_amdgcn_cvt_pkrtz(pe[6],  pe[7]);
    pb1.h2[0] = __builtin_amdgcn_cvt_pkrtz(pe[8],  pe[9]);
    pb1.h2[1] = __builtin_amdgcn_cvt_pkrtz(pe[10], pe[11]);
    pb1.h2[2] = __builtin_amdgcn_cvt_pkrtz(pe[12], pe[13]);
    pb1.h2[3] = __builtin_amdgcn_cvt_pkrtz(pe[14], pe[15]);
}

// ---------------------------------------------------------------------------
// QKV projection (unchanged)
// ---------------------------------------------------------------------------
__global__ __launch_bounds__(256) void qkv_proj(
    const float* __restrict__ Aq, const float* __restrict__ Ak, const float* __restrict__ Av,
    const float* __restrict__ Wq, const float* __restrict__ Wk, const float* __restrict__ Wv,
    const float* __restrict__ bq, const float* __restrict__ bk, const float* __restrict__ bv,
    f16* __restrict__ Qh, f16* __restrict__ Kh, f16* __restrict__ Vh)
{
    const int z = blockIdx.z;
    const float* __restrict__ A    = (z == 0) ? Aq : (z == 1) ? Ak : Av;
    const float* __restrict__ W    = (z == 0) ? Wq : (z == 1) ? Wk : Wv;
    const float* __restrict__ bias = (z == 0) ? bq : (z == 1) ? bk : bv;
    f16* __restrict__ dst          = (z == 0) ? Qh : (z == 1) ? Kh : Vh;

    __shared__ __align__(16) f16 As[128 * 40];
    __shared__ __align__(16) f16 Ws[128 * 40];

    const int t  = threadIdx.x;
    const int m0 = blockIdx.y * 128;
    const int n0 = blockIdx.x * 128;
    const int w = t >> 6, lane = t & 63, lr = lane & 15, lg = lane >> 4;
    const int wr = w >> 1, wc = w & 1;

    f32x4 acc[4][4] = {};

    for (int k0 = 0; k0 < 512; k0 += 32) {
        #pragma unroll
        for (int it = 0; it < 2; ++it) {
            int c = t + it * 256;
            int row  = c >> 2;
            int col8 = (c & 3) * 8;

            const float* ga = A + (size_t)(m0 + row) * 512 + k0 + col8;
            float4v a0 = *(const float4v*)ga;
            float4v a1 = *(const float4v*)(ga + 4);
            half8 ha;
            ha[0] = (f16)a0[0]; ha[1] = (f16)a0[1]; ha[2] = (f16)a0[2]; ha[3] = (f16)a0[3];
            ha[4] = (f16)a1[0]; ha[5] = (f16)a1[1]; ha[6] = (f16)a1[2]; ha[7] = (f16)a1[3];
            *(half8*)&As[row * 40 + col8] = ha;

            const float* gw = W + (size_t)(n0 + row) * 512 + k0 + col8;
            float4v w0 = *(const float4v*)gw;
            float4v w1 = *(const float4v*)(gw + 4);
            half8 hw;
            hw[0] = (f16)w0[0]; hw[1] = (f16)w0[1]; hw[2] = (f16)w0[2]; hw[3] = (f16)w0[3];
            hw[4] = (f16)w1[0]; hw[5] = (f16)w1[1]; hw[6] = (f16)w1[2]; hw[7] = (f16)w1[3];
            *(half8*)&Ws[row * 40 + col8] = hw;
        }
        __syncthreads();

        half8 af[4], bf[4];
        #pragma unroll
        for (int i = 0; i < 4; ++i) {
            af[i] = *(const half8*)&As[(wr * 64 + i * 16 + lr) * 40 + lg * 8];
            bf[i] = *(const half8*)&Ws[(wc * 64 + i * 16 + lr) * 40 + lg * 8];
        }
        #pragma unroll
        for (int mi = 0; mi < 4; ++mi)
            #pragma unroll
            for (int ni = 0; ni < 4; ++ni)
                acc[mi][ni] = __builtin_amdgcn_mfma_f32_16x16x32_f16(af[mi], bf[ni], acc[mi][ni], 0, 0, 0);
        __syncthreads();
    }

    #pragma unroll
    for (int mi = 0; mi < 4; ++mi) {
        #pragma unroll
        for (int ni = 0; ni < 4; ++ni) {
            int col = n0 + wc * 64 + ni * 16 + lr;
            float bv_ = bias[col];
            int h  = col >> 6;
            int dd = col & 63;
            #pragma unroll
            for (int r = 0; r < 4; ++r) {
                int row = m0 + wr * 64 + mi * 16 + lg * 4 + r;
                int b = row >> 12;
                int s = row & 4095;
                dst[(((size_t)(b * 8 + h)) * 4096 + s) * 64 + dd] = (f16)(acc[mi][ni][r] + bv_);
            }
        }
    }
}

// ---------------------------------------------------------------------------
// Flash attention v8 = round-8 kernel with VALU thinning:
//  - l row-sum via MFMA (A = ones): la = mfma(ones, pb, la); la[0] = l.
//    Removes the per-tile adds + DS shuffles for l entirely.
//  - sf init via constant-zero C operand (no per-tile v_mov zero-fill).
//  - TR8 issued between max-reduce (DS shuffles done) and exp/pack (pure
//    VALU) so tr-read latency hides under the exp phase.
// Everything else identical to round 8 (passing).
// ---------------------------------------------------------------------------
__global__ __launch_bounds__(256, 2) void flash_attn(
    const f16* __restrict__ Qh, const f16* __restrict__ Kh, const f16* __restrict__ Vh,
    f16* __restrict__ Xh)
{
    const int bh  = blockIdx.y;           // 0..15  (b*8 + h)
    const int t = threadIdx.x, w = t >> 6, lane = t & 63, lr = lane & 15, lg = lane >> 4;
    const int q0 = blockIdx.x * 128 + w * 32;

    __shared__ __align__(16) f16 Ks[2][64 * 72];   // [key][d], stride 72
    __shared__ __align__(16) f16 Vs[2][64 * 64];   // subtiled for tr_b16 reads

    const size_t hb = (size_t)bh * (4096 * 64);

    // Q fragments (B-operand of swapped QK^T) for both 16-row groups
    half8 aq00 = *(const half8*)&Qh[hb + (size_t)(q0 + lr) * 64 + lg * 8];
    half8 aq01 = *(const half8*)&Qh[hb + (size_t)(q0 + lr) * 64 + 32 + lg * 8];
    half8 aq10 = *(const half8*)&Qh[hb + (size_t)(q0 + 16 + lr) * 64 + lg * 8];
    half8 aq11 = *(const half8*)&Qh[hb + (size_t)(q0 + 16 + lr) * 64 + 32 + lg * 8];

    // loop-invariant MFMA constants
    half8 ones;
    #pragma unroll
    for (int j = 0; j < 8; ++j) ones[j] = (f16)1.0f;
    const f32x4 zf = {0.0f, 0.0f, 0.0f, 0.0f};

    // staging: 256 threads x 2 key-rows x 8 f16 per buffer
    const int srow = t >> 3;            // key index 0..31 (plus srow+32)
    const int scol = (t & 7) * 8;       // d index
    const int kdstA = srow * 72 + scol;
    const int kdstB = kdstA + 32 * 72;
    const int vdstA = ((((srow >> 2) & 3) * 16) + (srow >> 4) * 4 + (scol >> 4)) * 64
                    + (srow & 3) * 16 + (scol & 15);
    const int vdstB = vdstA + 512;      // vdst(srow+32) == vdst(srow) + 512

    f32x4 o0[4] = {}, o1[4] = {};
    f32x4 la0 = {}, la1 = {};           // l accumulators in MFMA D-layout
    float mL0 = -INFINITY, mL1 = -INFINITY;

    const f16* kbase = Kh + hb + (size_t)srow * 64 + scol;
    const f16* vbase = Vh + hb + (size_t)srow * 64 + scol;

    half8 kregA = *(const half8*)kbase;
    half8 kregB = *(const half8*)(kbase + 2048);
    half8 vregA = *(const half8*)vbase;
    half8 vregB = *(const half8*)(vbase + 2048);

    for (int kt = 0; kt < 4096; kt += 64) {
        const int bi = (kt >> 6) & 1;
        f16* ks = &Ks[bi][0];
        f16* vs = &Vs[bi][0];

        *(half8*)&ks[kdstA] = kregA;
        *(half8*)&ks[kdstB] = kregB;
        *(half8*)&vs[vdstA] = vregA;
        *(half8*)&vs[vdstB] = vregB;
        __syncthreads();

        // prefetch next tile into regs (hides HBM under compute)
        int koff = ((kt + 64) & 4095) << 6;
        kregA = *(const half8*)(kbase + koff);
        kregB = *(const half8*)(kbase + 2048 + koff);
        vregA = *(const half8*)(vbase + koff);
        vregB = *(const half8*)(vbase + 2048 + koff);

        // ---- S^T = K Q^T for both q-groups; kf loaded once, used twice ----
        f32x4 sf0[4], sf1[4];
        {
            half8 kf[4];
            #pragma unroll
            for (int kb = 0; kb < 4; ++kb)
                kf[kb] = *(const half8*)&ks[(kb * 16 + lr) * 72 + lg * 8];
            __builtin_amdgcn_s_setprio(1);
            #pragma unroll
            for (int kb = 0; kb < 4; ++kb)
                sf0[kb] = __builtin_amdgcn_mfma_f32_16x16x32_f16(kf[kb], aq00, zf, 0, 0, 0);
            #pragma unroll
            for (int kb = 0; kb < 4; ++kb)
                sf1[kb] = __builtin_amdgcn_mfma_f32_16x16x32_f16(kf[kb], aq10, zf, 0, 0, 0);
            __builtin_amdgcn_s_setprio(0);
            #pragma unroll
            for (int kb = 0; kb < 4; ++kb)
                kf[kb] = *(const half8*)&ks[(kb * 16 + lr) * 72 + 32 + lg * 8];
            __builtin_amdgcn_s_setprio(1);
            #pragma unroll
            for (int kb = 0; kb < 4; ++kb)
                sf0[kb] = __builtin_amdgcn_mfma_f32_16x16x32_f16(kf[kb], aq01, sf0[kb], 0, 0, 0);
            #pragma unroll
            for (int kb = 0; kb < 4; ++kb)
                sf1[kb] = __builtin_amdgcn_mfma_f32_16x16x32_f16(kf[kb], aq11, sf1[kb], 0, 0, 0);
            __builtin_amdgcn_s_setprio(0);
        }

        // ---- max-reduce + defer (all DS shuffles complete before TR8) ----
        max_defer(sf0, mL0, o0, la0);
        max_defer(sf1, mL1, o1, la1);

        // ---- issue V transpose-reads; exp/pack (pure VALU) hides latency --
        const unsigned vb = (unsigned)(size_t)vs + (unsigned)(lg * 2048 + lr * 8);
        half4 ua0,ua1,ua2,ua3,ua4,ua5,ua6,ua7;
        half4 ub0,ub1,ub2,ub3,ub4,ub5,ub6,ub7;
        TR8(vb,         ua0,ua1,ua2,ua3,ua4,ua5,ua6,ua7);
        TR8(vb + 1024u, ub0,ub1,ub2,ub3,ub4,ub5,ub6,ub7);

        H8 p00, p01, p10, p11;
        exp_pack(sf0, mL0, p00, p01);
        exp_pack(sf1, mL1, p10, p11);

        LGKM0_FENCE();

        // ---- O^T += V^T P^T ; l += ones x P (MFMA row-sum) ----
        __builtin_amdgcn_s_setprio(1);
        o0[0] = __builtin_amdgcn_mfma_f32_16x16x32_f16(cat8(ua0,ua1), p00.h8, o0[0], 0, 0, 0);
        o0[1] = __builtin_amdgcn_mfma_f32_16x16x32_f16(cat8(ua2,ua3), p00.h8, o0[1], 0, 0, 0);
        o0[2] = __builtin_amdgcn_mfma_f32_16x16x32_f16(cat8(ua4,ua5), p00.h8, o0[2], 0, 0, 0);
        o0[3] = __builtin_amdgcn_mfma_f32_16x16x32_f16(cat8(ua6,ua7), p00.h8, o0[3], 0, 0, 0);
        o1[0] = __builtin_amdgcn_mfma_f32_16x16x32_f16(cat8(ua0,ua1), p10.h8, o1[0], 0, 0, 0);
        o1[1] = __builtin_amdgcn_mfma_f32_16x16x32_f16(cat8(ua2,ua3), p10.h8, o1[1], 0, 0, 0);
        o1[2] = __builtin_amdgcn_mfma_f32_16x16x32_f16(cat8(ua4,ua5), p10.h8, o1[2], 0, 0, 0);
        o1[3] = __builtin_amdgcn_mfma_f32_16x16x32_f16(cat8(ua6,ua7), p10.h8, o1[3], 0, 0, 0);
        la0 = __builtin_amdgcn_mfma_f32_16x16x32_f16(ones, p00.h8, la0, 0, 0, 0);
        la1 = __builtin_amdgcn_mfma_f32_16x16x32_f16(ones, p10.h8, la1, 0, 0, 0);
        o0[0] = __builtin_amdgcn_mfma_f32_16x16x32_f16(cat8(ub0,ub1), p01.h8, o0[0], 0, 0, 0);
        o0[1] = __builtin_amdgcn_mfma_f32_16x16x32_f16(cat8(ub2,ub3), p01.h8, o0[1], 0, 0, 0);
        o0[2] = __builtin_amdgcn_mfma_f32_16x16x32_f16(cat8(ub4,ub5), p01.h8, o0[2], 0, 0, 0);
        o0[3] = __builtin_amdgcn_mfma_f32_16x16x32_f16(cat8(ub6,ub7), p01.h8, o0[3], 0, 0, 0);
        o1[0] = __builtin_amdgcn_mfma_f32_16x16x32_f16(cat8(ub0,ub1), p11.h8, o1[0], 0, 0, 0);
        o1[1] = __builtin_amdgcn_mfma_f32_16x16x32_f16(cat8(ub2,ub3), p11.h8, o1[1], 0, 0, 0);
        o1[2] = __builtin_amdgcn_mfma_f32_16x16x32_f16(cat8(ub4,ub5), p11.h8, o1[2], 0, 0, 0);
        o1[3] = __builtin_amdgcn_mfma_f32_16x16x32_f16(cat8(ub6,ub7), p11.h8, o1[3], 0, 0, 0);
        la0 = __builtin_amdgcn_mfma_f32_16x16x32_f16(ones, p01.h8, la0, 0, 0, 0);
        la1 = __builtin_amdgcn_mfma_f32_16x16x32_f16(ones, p11.h8, la1, 0, 0, 0);
        __builtin_amdgcn_s_setprio(0);
    }

    // ---- epilogue: O/(l*8) per group; l = la[0] (rows identical) ----
    const int b = bh >> 3, h = bh & 7;
    const float inv0 = 1.0f / (la0[0] * 8.0f);
    const float inv1 = 1.0f / (la1[0] * 8.0f);
    const int q0_ = q0 + lr, q1_ = q0 + 16 + lr;
    #pragma unroll
    for (int db = 0; db < 4; ++db) {
        half4 hv0, hv1;
        hv0[0] = (f16)(o0[db][0] * inv0);
        hv0[1] = (f16)(o0[db][1] * inv0);
        hv0[2] = (f16)(o0[db][2] * inv0);
        hv0[3] = (f16)(o0[db][3] * inv0);
        *(half4*)&Xh[((size_t)(b * 4096 + q0_)) * 512 + h * 64 + db * 16 + lg * 4] = hv0;
        hv1[0] = (f16)(o1[db][0] * inv1);
        hv1[1] = (f16)(o1[db][1] * inv1);
        hv1[2] = (f16)(o1[db][2] * inv1);
        hv1[3] = (f16)(o1[db][3] * inv1);
        *(half4*)&Xh[((size_t)(b * 4096 + q1_)) * 512 + h * 64 + db * 16 + lg * 4] = hv1;
    }
}

// ---------------------------------------------------------------------------
// Output projection (unchanged)
// ---------------------------------------------------------------------------
__global__ __launch_bounds__(256) void out_proj(
    const f16* __restrict__ Xh, const float* __restrict__ Wo, const float* __restrict__ bo,
    float* __restrict__ out)
{
    __shared__ __align__(16) f16 As[128 * 40];
    __shared__ __align__(16) f16 Ws[128 * 40];

    const int t  = threadIdx.x;
    const int m0 = blockIdx.y * 128;
    const int n0 = blockIdx.x * 128;
    const int w = t >> 6, lane = t & 63, lr = lane & 15, lg = lane >> 4;
    const int wr = w >> 1, wc = w & 1;

    f32x4 acc[4][4] = {};

    for (int k0 = 0; k0 < 512; k0 += 32) {
        #pragma unroll
        for (int it = 0; it < 2; ++it) {
            int c = t + it * 256;
            int row  = c >> 2;
            int col8 = (c & 3) * 8;

            *(half8*)&As[row * 40 + col8] =
                *(const half8*)&Xh[(size_t)(m0 + row) * 512 + k0 + col8];

            const float* gw = Wo + (size_t)(n0 + row) * 512 + k0 + col8;
            float4v w0 = *(const float4v*)gw;
            float4v w1 = *(const float4v*)(gw + 4);
            half8 hw;
            hw[0] = (f16)w0[0]; hw[1] = (f16)w0[1]; hw[2] = (f16)w0[2]; hw[3] = (f16)w0[3];
            hw[4] = (f16)w1[0]; hw[5] = (f16)w1[1]; hw[6] = (f16)w1[2]; hw[7] = (f16)w1[3];
            *(half8*)&Ws[row * 40 + col8] = hw;
        }
        __syncthreads();

        half8 af[4], bf[4];
        #pragma unroll
        for (int i = 0; i < 4; ++i) {
            af[i] = *(const half8*)&As[(wr * 64 + i * 16 + lr) * 40 + lg * 8];
            bf[i] = *(const half8*)&Ws[(wc * 64 + i * 16 + lr) * 40 + lg * 8];
        }
        #pragma unroll
        for (int mi = 0; mi < 4; ++mi)
            #pragma unroll
            for (int ni = 0; ni < 4; ++ni)
                acc[mi][ni] = __builtin_amdgcn_mfma_f32_16x16x32_f16(af[mi], bf[ni], acc[mi][ni], 0, 0, 0);
        __syncthreads();
    }

    #pragma unroll
    for (int mi = 0; mi < 4; ++mi) {
        #pragma unroll
        for (int ni = 0; ni < 4; ++ni) {
            int col = n0 + wc * 64 + ni * 16 + lr;
            float bb = bo[col];
            #pragma unroll
            for (int r = 0; r < 4; ++r) {
                int row = m0 + wr * 64 + mi * 16 + lg * 4 + r;
                out[(size_t)row * 512 + col] = acc[mi][ni][r] + bb;
            }
        }
    }
}

// ---------------------------------------------------------------------------
extern "C" void kernel_launch(void* const* d_in, const int* in_sizes, int n_in,
                              void* d_out, int out_size, void* d_ws, size_t ws_size,
                              hipStream_t stream) {
    const float* query = (const float*)d_in[0];
    const float* key   = (const float*)d_in[1];
    const float* value = (const float*)d_in[2];
    const float* Wq    = (const float*)d_in[3];
    const float* bq    = (const float*)d_in[4];
    const float* Wk    = (const float*)d_in[5];
    const float* bk    = (const float*)d_in[6];
    const float* Wv    = (const float*)d_in[7];
    const float* bv    = (const float*)d_in[8];
    const float* Wo    = (const float*)d_in[9];
    const float* bo    = (const float*)d_in[10];
    float* out = (float*)d_out;

    char* ws = (char*)d_ws;
    f16* Qh = (f16*)(ws);
    f16* Kh = (f16*)(ws + 8388608);
    f16* Vh = (f16*)(ws + 16777216);
    f16* Xh = (f16*)(ws + 25165824);

    qkv_proj<<<dim3(4, 64, 3), 256, 0, stream>>>(query, key, value,
                                                 Wq, Wk, Wv, bq, bk, bv,
                                                 Qh, Kh, Vh);
    flash_attn<<<dim3(32, 16), 256, 0, stream>>>(Qh, Kh, Vh, Xh);
    out_proj<<<dim3(4, 64), 256, 0, stream>>>(Xh, Wo, bo, out);
}